// Round 3
// baseline (475.607 us; speedup 1.0000x reference)
//
#include <hip/hip_runtime.h>

typedef __attribute__((ext_vector_type(8))) __bf16 bf16x8;
typedef __attribute__((ext_vector_type(4))) float f32x4;

__device__ __forceinline__ unsigned short f32_to_bf16(float f) {
    unsigned int u = __float_as_uint(f);
    u += 0x7FFFu + ((u >> 16) & 1u);   // RNE
    return (unsigned short)(u >> 16);
}

// ---------------------------------------------------------------------------
// Kernel 0: weight prep. Build Wbp[c][k] bf16 (N-major, 512x512) where
// column c = V[:, c/2] if c even else U[:, c/2]; also permuted bias and w.
// ---------------------------------------------------------------------------
__global__ __launch_bounds__(256) void prep_weights(
    const float* __restrict__ Vw, const float* __restrict__ Uw,
    const float* __restrict__ Vb, const float* __restrict__ Ub,
    const float* __restrict__ ww,
    unsigned short* __restrict__ Wbp, float* __restrict__ bperm,
    float* __restrict__ wpair) {
    int id = blockIdx.x * 256 + threadIdx.x;   // 512*512 total
    int c = id >> 9, k = id & 511;
    int j = c >> 1;
    float v = (c & 1) ? Uw[k * 256 + j] : Vw[k * 256 + j];
    Wbp[c * 512 + k] = f32_to_bf16(v);
    if (id < 512) bperm[id] = (id & 1) ? Ub[id >> 1] : Vb[id >> 1];
    if (id < 256) wpair[id] = ww[id];
}

// ---------------------------------------------------------------------------
// Kernel 1: fused GEMM + gated score.
// Block: 64 rows x 512 cols (all of [V|U] interleaved). 512 threads = 8 waves,
// each wave 64 rows x 64 cols (= 32 (V,U) column pairs).
// A tile staged in LDS as bf16 with 16B XOR swizzle; B read from global (L2).
// Epilogue: z pairs via shfl_xor(1), s = sum tanh(zV)*sigmoid(zU)*w per row.
// ---------------------------------------------------------------------------
__global__ __launch_bounds__(512) void gemm_score(
    const float* __restrict__ x, const unsigned short* __restrict__ Wbp,
    const float* __restrict__ bperm, const float* __restrict__ wpair,
    float* __restrict__ s_out, int M) {
    __shared__ unsigned char lds[64 * 1024];
    const int tid = threadIdx.x;
    const int row0 = blockIdx.x * 64;

    // ---- stage A: 64 rows x 512 k, f32 -> bf16, swizzled 16B chunks
    for (int i = 0; i < 8; ++i) {
        int q = i * 512 + tid;          // chunk id, 64 rows * 64 chunks
        int r = q >> 6;
        int c16 = q & 63;
        int grow = row0 + r; if (grow >= M) grow = M - 1;
        const float* src = x + (size_t)grow * 512 + c16 * 8;
        float4 f0 = *(const float4*)(src);
        float4 f1 = *(const float4*)(src + 4);
        uint4 p;
        p.x = (unsigned)f32_to_bf16(f0.x) | ((unsigned)f32_to_bf16(f0.y) << 16);
        p.y = (unsigned)f32_to_bf16(f0.z) | ((unsigned)f32_to_bf16(f0.w) << 16);
        p.z = (unsigned)f32_to_bf16(f1.x) | ((unsigned)f32_to_bf16(f1.y) << 16);
        p.w = (unsigned)f32_to_bf16(f1.z) | ((unsigned)f32_to_bf16(f1.w) << 16);
        int swc = c16 ^ (r & 7);
        *(uint4*)(lds + r * 1024 + swc * 16) = p;
    }
    __syncthreads();

    const int l = tid & 63;
    const int w = tid >> 6;
    const int lr = l & 15;
    const int lg = l >> 4;
    const int wcol0 = w * 64;

    f32x4 acc[4][4];
    for (int mt = 0; mt < 4; ++mt)
        for (int nt = 0; nt < 4; ++nt)
            acc[mt][nt] = (f32x4){0.f, 0.f, 0.f, 0.f};

    const unsigned short* bptr[4];
    for (int nt = 0; nt < 4; ++nt)
        bptr[nt] = Wbp + (size_t)(wcol0 + nt * 16 + lr) * 512 + lg * 8;

    for (int k0 = 0; k0 < 512; k0 += 32) {
        bf16x8 a[4], b[4];
        int cpre = (k0 >> 3) + lg;
#pragma unroll
        for (int mt = 0; mt < 4; ++mt) {
            int r = mt * 16 + lr;
            a[mt] = *(const bf16x8*)(lds + r * 1024 + ((cpre ^ (r & 7)) << 4));
        }
#pragma unroll
        for (int nt = 0; nt < 4; ++nt)
            b[nt] = *(const bf16x8*)(bptr[nt] + k0);
#pragma unroll
        for (int mt = 0; mt < 4; ++mt)
#pragma unroll
            for (int nt = 0; nt < 4; ++nt)
                acc[mt][nt] = __builtin_amdgcn_mfma_f32_16x16x32_bf16(
                    a[mt], b[nt], acc[mt][nt], 0, 0, 0);
    }

    // ---- epilogue: C(row,col): col = wcol0+nt*16+lr, row = mt*16+lg*4+r
    float rowsum[4][4];
    for (int mt = 0; mt < 4; ++mt)
        for (int r = 0; r < 4; ++r) rowsum[mt][r] = 0.f;

#pragma unroll
    for (int nt = 0; nt < 4; ++nt) {
        int col = wcol0 + nt * 16 + lr;
        float bia = bperm[col];
        float wp = wpair[col >> 1];
#pragma unroll
        for (int mt = 0; mt < 4; ++mt)
#pragma unroll
            for (int r = 0; r < 4; ++r) {
                float z = acc[mt][nt][r] + bia;
                float pz = __shfl_xor(z, 1, 64);   // partner column (U for even)
                float contrib = 0.f;
                if (!(l & 1)) {
                    float av = tanhf(z);
                    float au = 1.f / (1.f + expf(-pz));
                    contrib = av * au * wp;
                }
                rowsum[mt][r] += contrib;
            }
    }

    // reduce over the 8 even lanes of each 16-lane group (odd lanes hold 0)
#pragma unroll
    for (int mt = 0; mt < 4; ++mt)
#pragma unroll
        for (int r = 0; r < 4; ++r) {
            float v = rowsum[mt][r];
            v += __shfl_xor(v, 1, 64);
            v += __shfl_xor(v, 2, 64);
            v += __shfl_xor(v, 4, 64);
            v += __shfl_xor(v, 8, 64);
            rowsum[mt][r] = v;
        }

    __syncthreads();                       // done reading A tile
    float* sred = (float*)lds;             // [8 waves][64 rows]
    if (lr == 0) {
#pragma unroll
        for (int mt = 0; mt < 4; ++mt)
#pragma unroll
            for (int r = 0; r < 4; ++r)
                sred[w * 64 + mt * 16 + lg * 4 + r] = rowsum[mt][r];
    }
    __syncthreads();
    if (tid < 64) {
        float s = 0.f;
#pragma unroll
        for (int ww_ = 0; ww_ < 8; ++ww_) s += sred[ww_ * 64 + tid];
        int node = row0 + tid;
        if (node < M) s_out[node] = s;     // w_b omitted: softmax-invariant
    }
}

// ---------------------------------------------------------------------------
// Kernel 2: per-segment softmax. Block g handles [ptr[g], ptr[g+1]).
// Last block also WRITES att for tail nodes [ptr[nseg], ntot) using its
// max/sum (JAX out-of-range clamp semantics) without including them.
// NOTE: ptr arrives as int32 on device (harness converts all ints to int32).
// ---------------------------------------------------------------------------
__global__ __launch_bounds__(256) void seg_softmax(
    const float* __restrict__ s, const int* __restrict__ ptr,
    float* __restrict__ att, int nseg, int ntot) {
    __shared__ float red[4];
    __shared__ float bmax, bsum;
    int g = blockIdx.x, tid = threadIdx.x;
    int i0 = ptr[g], i1 = ptr[g + 1];
    if (i0 < 0) i0 = 0;  if (i0 > ntot) i0 = ntot;
    if (i1 < i0) i1 = i0; if (i1 > ntot) i1 = ntot;
    int iw1 = (g == nseg - 1) ? ntot : i1;

    float m = -3.4e38f;
    for (int i = i0 + tid; i < i1; i += 256) m = fmaxf(m, s[i]);
    for (int o = 1; o < 64; o <<= 1) m = fmaxf(m, __shfl_xor(m, o, 64));
    if ((tid & 63) == 0) red[tid >> 6] = m;
    __syncthreads();
    if (tid == 0)
        bmax = fmaxf(fmaxf(red[0], red[1]), fmaxf(red[2], red[3]));
    __syncthreads();
    m = bmax;

    float sum = 0.f;
    for (int i = i0 + tid; i < i1; i += 256) sum += expf(s[i] - m);
    for (int o = 1; o < 64; o <<= 1) sum += __shfl_xor(sum, o, 64);
    if ((tid & 63) == 0) red[tid >> 6] = sum;
    __syncthreads();
    if (tid == 0) bsum = red[0] + red[1] + red[2] + red[3];
    __syncthreads();
    float inv = 1.f / bsum;

    for (int i = i0 + tid; i < iw1; i += 256) att[i] = expf(s[i] - m) * inv;
}

// ---------------------------------------------------------------------------
// Kernel 3: x_graphs[g] = sum over segment nodes of att[i] * x[i].
// Grid = nseg * CH blocks; each block a node-chunk, 512 threads = 512 dims.
// ---------------------------------------------------------------------------
__global__ __launch_bounds__(512) void seg_weighted_sum(
    const float* __restrict__ x, const float* __restrict__ att,
    const int* __restrict__ ptr, float* __restrict__ xg, int chunks) {
    int g = blockIdx.x / chunks, c = blockIdx.x % chunks;
    int d = threadIdx.x;
    int i0 = ptr[g], i1 = ptr[g + 1];
    int len = i1 - i0;
    int n0 = i0 + (int)(((long long)len * c) / chunks);
    int n1 = i0 + (int)(((long long)len * (c + 1)) / chunks);
    float acc = 0.f;
    for (int i = n0; i < n1; ++i)
        acc += att[i] * x[(size_t)i * 512 + d];
    atomicAdd(&xg[(size_t)g * 512 + d], acc);
}

extern "C" void kernel_launch(void* const* d_in, const int* in_sizes, int n_in,
                              void* d_out, int out_size, void* d_ws, size_t ws_size,
                              hipStream_t stream) {
    const float* x   = (const float*)d_in[0];
    const int*   ptr = (const int*)d_in[1];   // harness: integer -> int32
    const float* Vw  = (const float*)d_in[2];
    const float* Vb  = (const float*)d_in[3];
    const float* Uw  = (const float*)d_in[4];
    const float* Ub  = (const float*)d_in[5];
    const float* ww  = (const float*)d_in[6];
    // d_in[7] = w_b: adds a constant to every score -> cancels in softmax.

    const int M    = in_sizes[0] / 512;   // 100000 nodes
    const int nseg = in_sizes[1] - 1;     // 64 graphs

    float* att = (float*)d_out;           // output 0: M floats
    float* xg  = (float*)d_out + M;       // output 1: nseg*512 floats

    unsigned short* Wbp   = (unsigned short*)d_ws;                 // 512*512 bf16
    float*          bperm = (float*)((char*)d_ws + 512 * 512 * 2); // 512 f32
    float*          wpair = bperm + 512;                           // 256 f32
    float*          s_all = wpair + 256;                           // M f32

    prep_weights<<<1024, 256, 0, stream>>>(Vw, Uw, Vb, Ub, ww, Wbp, bperm, wpair);
    gemm_score<<<(M + 63) / 64, 512, 0, stream>>>(x, Wbp, bperm, wpair, s_all, M);
    seg_softmax<<<nseg, 256, 0, stream>>>(s_all, ptr, att, nseg, M);
    hipMemsetAsync(xg, 0, (size_t)nseg * 512 * sizeof(float), stream);
    const int CH = 8;
    seg_weighted_sum<<<nseg * CH, 512, 0, stream>>>(x, att, ptr, xg, CH);
}

// Round 5
// 419.010 us; speedup vs baseline: 1.1351x; 1.1351x over previous
//
#include <hip/hip_runtime.h>

typedef __attribute__((ext_vector_type(8))) __bf16 bf16x8;
typedef __attribute__((ext_vector_type(4))) float f32x4;

// ---------------------------------------------------------------------------
// Kernel 0: weight prep. Transpose V_w,U_w (512x256, K-major) into N-major
// bf16 matrices Vb16[c][k], Ub16[c][k] (256x512 each).
// ---------------------------------------------------------------------------
__global__ __launch_bounds__(256) void prep_weights(
    const float* __restrict__ Vw, const float* __restrict__ Uw,
    __bf16* __restrict__ Vb16, __bf16* __restrict__ Ub16) {
    int id = blockIdx.x * 256 + threadIdx.x;   // 256*512 total
    int c = id >> 9, k = id & 511;
    Vb16[id] = (__bf16)Vw[k * 256 + c];
    Ub16[id] = (__bf16)Uw[k * 256 + c];
}

// ---------------------------------------------------------------------------
// Kernel 1: fused GEMM + gated score.
// Block: 64 rows, 512 threads = 8 waves. Wave w computes V-cols AND U-cols
// [32w, 32w+32) for all 64 rows -> zV and zU live in the same lane.
// A staged full-K in LDS (bf16, 16B XOR swizzle); B read from global (L2).
// Epilogue: s_row = sum_j tanh(zV_j)*sigmoid(zU_j)*w_j, branch-free exp/rcp.
// ---------------------------------------------------------------------------
__global__ __launch_bounds__(512) void gemm_score(
    const float* __restrict__ x, const __bf16* __restrict__ Vb16,
    const __bf16* __restrict__ Ub16, const float* __restrict__ Vb,
    const float* __restrict__ Ub, const float* __restrict__ ww,
    float* __restrict__ s_out, int M) {
    __shared__ unsigned char lds[64 * 1024];
    const int tid = threadIdx.x;
    const int row0 = blockIdx.x * 64;

    // ---- stage A: 64 rows x 512 k, f32 -> bf16, swizzled 16B chunks
    for (int i = 0; i < 8; ++i) {
        int q = i * 512 + tid;          // chunk id: 64 rows * 64 chunks
        int r = q >> 6;
        int c16 = q & 63;
        int grow = row0 + r; if (grow >= M) grow = M - 1;
        const float* src = x + (size_t)grow * 512 + c16 * 8;
        float4 f0 = *(const float4*)(src);
        float4 f1 = *(const float4*)(src + 4);
        bf16x8 p;
        p[0] = (__bf16)f0.x; p[1] = (__bf16)f0.y;
        p[2] = (__bf16)f0.z; p[3] = (__bf16)f0.w;
        p[4] = (__bf16)f1.x; p[5] = (__bf16)f1.y;
        p[6] = (__bf16)f1.z; p[7] = (__bf16)f1.w;
        int swc = c16 ^ (r & 7);
        *(bf16x8*)(lds + r * 1024 + swc * 16) = p;
    }
    __syncthreads();

    const int l = tid & 63;
    const int w = tid >> 6;
    const int lr = l & 15;
    const int lg = l >> 4;
    const int wcol0 = w * 32;           // within 256-col V (and U) space

    f32x4 aV[4][2], aU[4][2];
    for (int mt = 0; mt < 4; ++mt)
        for (int nt = 0; nt < 2; ++nt) {
            aV[mt][nt] = (f32x4){0.f, 0.f, 0.f, 0.f};
            aU[mt][nt] = (f32x4){0.f, 0.f, 0.f, 0.f};
        }

    const __bf16* bpV[2];
    const __bf16* bpU[2];
    for (int nt = 0; nt < 2; ++nt) {
        size_t off = (size_t)(wcol0 + nt * 16 + lr) * 512 + lg * 8;
        bpV[nt] = Vb16 + off;
        bpU[nt] = Ub16 + off;
    }

    for (int k0 = 0; k0 < 512; k0 += 32) {
        bf16x8 a[4], bV[2], bU[2];
        int cpre = (k0 >> 3) + lg;
#pragma unroll
        for (int mt = 0; mt < 4; ++mt) {
            int r = mt * 16 + lr;
            a[mt] = *(const bf16x8*)(lds + r * 1024 + ((cpre ^ (r & 7)) << 4));
        }
#pragma unroll
        for (int nt = 0; nt < 2; ++nt) {
            bV[nt] = *(const bf16x8*)(bpV[nt] + k0);
            bU[nt] = *(const bf16x8*)(bpU[nt] + k0);
        }
#pragma unroll
        for (int mt = 0; mt < 4; ++mt)
#pragma unroll
            for (int nt = 0; nt < 2; ++nt) {
                aV[mt][nt] = __builtin_amdgcn_mfma_f32_16x16x32_bf16(
                    a[mt], bV[nt], aV[mt][nt], 0, 0, 0);
                aU[mt][nt] = __builtin_amdgcn_mfma_f32_16x16x32_bf16(
                    a[mt], bU[nt], aU[mt][nt], 0, 0, 0);
            }
    }

    // ---- epilogue: C(row,col): col = wcol0+nt*16+lr, row = mt*16+lg*4+r
    float rowsum[4][4];
    for (int mt = 0; mt < 4; ++mt)
        for (int r = 0; r < 4; ++r) rowsum[mt][r] = 0.f;

#pragma unroll
    for (int nt = 0; nt < 2; ++nt) {
        int col = wcol0 + nt * 16 + lr;
        float bv = Vb[col];
        float bu = Ub[col];
        float wj = ww[col];
#pragma unroll
        for (int mt = 0; mt < 4; ++mt)
#pragma unroll
            for (int r = 0; r < 4; ++r) {
                float zv = aV[mt][nt][r] + bv;
                float zu = aU[mt][nt][r] + bu;
                // tanh(zv) = 1 - 2/(e^{2zv}+1); saturates correctly at +-inf
                float t  = 1.f - 2.f * __builtin_amdgcn_rcpf(__expf(2.f * zv) + 1.f);
                float sg = __builtin_amdgcn_rcpf(1.f + __expf(-zu));
                rowsum[mt][r] += t * sg * wj;
            }
    }

    // reduce over the 16 lanes (lr) of each lane-group
#pragma unroll
    for (int mt = 0; mt < 4; ++mt)
#pragma unroll
        for (int r = 0; r < 4; ++r) {
            float v = rowsum[mt][r];
            v += __shfl_xor(v, 1, 64);
            v += __shfl_xor(v, 2, 64);
            v += __shfl_xor(v, 4, 64);
            v += __shfl_xor(v, 8, 64);
            rowsum[mt][r] = v;
        }

    __syncthreads();                       // done reading A tile
    float* sred = (float*)lds;             // [8 waves][64 rows]
    if (lr == 0) {
#pragma unroll
        for (int mt = 0; mt < 4; ++mt)
#pragma unroll
            for (int r = 0; r < 4; ++r)
                sred[w * 64 + mt * 16 + lg * 4 + r] = rowsum[mt][r];
    }
    __syncthreads();
    if (tid < 64) {
        float s = 0.f;
#pragma unroll
        for (int ww_ = 0; ww_ < 8; ++ww_) s += sred[ww_ * 64 + tid];
        int node = row0 + tid;
        if (node < M) s_out[node] = s;     // w_b omitted: softmax-invariant
    }
}

// ---------------------------------------------------------------------------
// Kernel 2: per-segment softmax. Block g handles [ptr[g], ptr[g+1]).
// Last block also WRITES att for tail nodes [ptr[nseg], ntot) using its
// max/sum (JAX out-of-range clamp semantics) without including them.
// ptr is int32 on device (harness converts integer inputs to int32).
// ---------------------------------------------------------------------------
__global__ __launch_bounds__(256) void seg_softmax(
    const float* __restrict__ s, const int* __restrict__ ptr,
    float* __restrict__ att, int nseg, int ntot) {
    __shared__ float red[4];
    __shared__ float bmax, bsum;
    int g = blockIdx.x, tid = threadIdx.x;
    int i0 = ptr[g], i1 = ptr[g + 1];
    if (i0 < 0) i0 = 0;  if (i0 > ntot) i0 = ntot;
    if (i1 < i0) i1 = i0; if (i1 > ntot) i1 = ntot;
    int iw1 = (g == nseg - 1) ? ntot : i1;

    float m = -3.4e38f;
    for (int i = i0 + tid; i < i1; i += 256) m = fmaxf(m, s[i]);
    for (int o = 1; o < 64; o <<= 1) m = fmaxf(m, __shfl_xor(m, o, 64));
    if ((tid & 63) == 0) red[tid >> 6] = m;
    __syncthreads();
    if (tid == 0)
        bmax = fmaxf(fmaxf(red[0], red[1]), fmaxf(red[2], red[3]));
    __syncthreads();
    m = bmax;

    float sum = 0.f;
    for (int i = i0 + tid; i < i1; i += 256) sum += __expf(s[i] - m);
    for (int o = 1; o < 64; o <<= 1) sum += __shfl_xor(sum, o, 64);
    if ((tid & 63) == 0) red[tid >> 6] = sum;
    __syncthreads();
    if (tid == 0) bsum = red[0] + red[1] + red[2] + red[3];
    __syncthreads();
    float inv = 1.f / bsum;

    for (int i = i0 + tid; i < iw1; i += 256) att[i] = __expf(s[i] - m) * inv;
}

// ---------------------------------------------------------------------------
// Kernel 3: x_graphs[g] = sum over segment nodes of att[i] * x[i].
// Grid = nseg * CH blocks; 512 threads = 512 dims; 4-way unrolled rows
// (4 independent accumulators -> 4 outstanding HBM loads per wave).
// ---------------------------------------------------------------------------
__global__ __launch_bounds__(512) void seg_weighted_sum(
    const float* __restrict__ x, const float* __restrict__ att,
    const int* __restrict__ ptr, float* __restrict__ xg, int chunks) {
    int g = blockIdx.x / chunks, c = blockIdx.x % chunks;
    int d = threadIdx.x;
    int i0 = ptr[g], i1 = ptr[g + 1];
    int len = i1 - i0;
    int n0 = i0 + (int)(((long long)len * c) / chunks);
    int n1 = i0 + (int)(((long long)len * (c + 1)) / chunks);
    float a0 = 0.f, a1 = 0.f, a2 = 0.f, a3 = 0.f;
    int i = n0;
    for (; i + 3 < n1; i += 4) {
        float t0 = att[i], t1 = att[i + 1], t2 = att[i + 2], t3 = att[i + 3];
        a0 += t0 * x[(size_t)(i    ) * 512 + d];
        a1 += t1 * x[(size_t)(i + 1) * 512 + d];
        a2 += t2 * x[(size_t)(i + 2) * 512 + d];
        a3 += t3 * x[(size_t)(i + 3) * 512 + d];
    }
    for (; i < n1; ++i) a0 += att[i] * x[(size_t)i * 512 + d];
    atomicAdd(&xg[(size_t)g * 512 + d], (a0 + a1) + (a2 + a3));
}

extern "C" void kernel_launch(void* const* d_in, const int* in_sizes, int n_in,
                              void* d_out, int out_size, void* d_ws, size_t ws_size,
                              hipStream_t stream) {
    const float* x   = (const float*)d_in[0];
    const int*   ptr = (const int*)d_in[1];   // harness: integer -> int32
    const float* Vw  = (const float*)d_in[2];
    const float* Vb  = (const float*)d_in[3];
    const float* Uw  = (const float*)d_in[4];
    const float* Ub  = (const float*)d_in[5];
    const float* ww  = (const float*)d_in[6];
    // d_in[7] = w_b: adds a constant to every score -> cancels in softmax.

    const int M    = in_sizes[0] / 512;   // 100000 nodes
    const int nseg = in_sizes[1] - 1;     // 64 graphs

    float* att = (float*)d_out;           // output 0: M floats
    float* xg  = (float*)d_out + M;       // output 1: nseg*512 floats

    __bf16* Vb16 = (__bf16*)d_ws;                          // 256*512 bf16
    __bf16* Ub16 = Vb16 + 256 * 512;                       // 256*512 bf16
    float*  s_all = (float*)(Ub16 + 256 * 512);            // M f32

    prep_weights<<<512, 256, 0, stream>>>(Vw, Uw, Vb16, Ub16);
    gemm_score<<<(M + 63) / 64, 512, 0, stream>>>(x, Vb16, Ub16, Vb, Ub, ww,
                                                  s_all, M);
    seg_softmax<<<nseg, 256, 0, stream>>>(s_all, ptr, att, nseg, M);
    hipMemsetAsync(xg, 0, (size_t)nseg * 512 * sizeof(float), stream);
    const int CH = 16;
    seg_weighted_sum<<<nseg * CH, 512, 0, stream>>>(x, att, ptr, xg, CH);
}

// Round 6
// 381.420 us; speedup vs baseline: 1.2469x; 1.0986x over previous
//
#include <hip/hip_runtime.h>

typedef __attribute__((ext_vector_type(8))) __bf16 bf16x8;
typedef __attribute__((ext_vector_type(4))) float f32x4;

__device__ __forceinline__ void fma4(float4& a, float t, const float4 v) {
    a.x += t * v.x; a.y += t * v.y; a.z += t * v.z; a.w += t * v.w;
}

// ---------------------------------------------------------------------------
// Kernel 0: weight prep -> MFMA-fragment-order bf16 layout.
// Fragment f = ((m*16+cb)*16+kb): 64 lanes x 16B, lane l holds
// col = cb*16 + (l&15), k = kb*32 + (l>>4)*8 + j  (j=0..7).
// A wave's B-load is then a contiguous 1KB global read.
// Total: 2 mats * 16 cb * 16 kb * 64 lanes * 8 elems = 256K bf16 = 512KB.
// ---------------------------------------------------------------------------
__global__ __launch_bounds__(256) void prep_weights(
    const float* __restrict__ Vw, const float* __restrict__ Uw,
    __bf16* __restrict__ Wfrag) {
    int id = blockIdx.x * 256 + threadIdx.x;     // 32768 threads
    int m  = id >> 14;
    int cb = (id >> 10) & 15;
    int kb = (id >> 6) & 15;
    int l  = id & 63;
    int col = cb * 16 + (l & 15);
    int k0  = kb * 32 + (l >> 4) * 8;
    const float* src = (m ? Uw : Vw) + (size_t)k0 * 256 + col;
    bf16x8 p;
#pragma unroll
    for (int j = 0; j < 8; ++j) p[j] = (__bf16)src[j * 256];
    *(bf16x8*)(Wfrag + (size_t)id * 8) = p;
}

// ---------------------------------------------------------------------------
// Kernel 1: fused GEMM + gated score. BM=64 rows, BK=128 double-buffered.
// 512 threads = 8 waves; wave w owns V-cols AND U-cols [32w, 32w+32).
// A: global f32 -> regs -> bf16 LDS (16B XOR swizzle, conflict-free);
// loads for chunk kc+1 issue before compute of chunk kc (latency hidden).
// B: fragment-order global (coalesced 1KB/wave, L2-resident).
// Epilogue: s_row = sum_j tanh(zV_j)*sigmoid(zU_j)*w_j, branch-free exp/rcp.
// ---------------------------------------------------------------------------
__global__ __launch_bounds__(512, 4) void gemm_score(
    const float* __restrict__ x, const __bf16* __restrict__ Wfrag,
    const float* __restrict__ Vb, const float* __restrict__ Ub,
    const float* __restrict__ ww, float* __restrict__ s_out, int M) {
    __shared__ unsigned char lds[2 * 16384];     // 2 x (64 rows x 128 k x bf16)
    const int tid  = threadIdx.x;
    const int row0 = blockIdx.x * 64;
    const int l  = tid & 63;
    const int w  = tid >> 6;
    const int lr = l & 15;
    const int lg = l >> 4;

    // staging geometry: 1024 16B-chunks per buffer; thread t -> chunks {t, t+512}
    const int r0 = tid >> 4;                 // 0..31
    const int r1 = r0 + 32;                  // 32..63
    const int c16 = tid & 15;
    int g0 = row0 + r0; if (g0 >= M) g0 = M - 1;
    int g1 = row0 + r1; if (g1 >= M) g1 = M - 1;
    const float* src0 = x + (size_t)g0 * 512 + c16 * 8;
    const float* src1 = x + (size_t)g1 * 512 + c16 * 8;
    const unsigned d0 = (unsigned)(r0 * 256 + ((c16 ^ (r0 & 15)) << 4));
    const unsigned d1 = (unsigned)(r1 * 256 + ((c16 ^ (r1 & 15)) << 4));

    float4 f0, f1, f2, f3;
#define LOADC(kc)                                                   \
    {                                                               \
        const float* p0 = src0 + (kc) * 128;                        \
        const float* p1 = src1 + (kc) * 128;                        \
        f0 = *(const float4*)(p0);  f1 = *(const float4*)(p0 + 4);  \
        f2 = *(const float4*)(p1);  f3 = *(const float4*)(p1 + 4);  \
    }
#define STOREC(b)                                                   \
    {                                                               \
        bf16x8 p;                                                   \
        p[0]=(__bf16)f0.x; p[1]=(__bf16)f0.y; p[2]=(__bf16)f0.z;    \
        p[3]=(__bf16)f0.w; p[4]=(__bf16)f1.x; p[5]=(__bf16)f1.y;    \
        p[6]=(__bf16)f1.z; p[7]=(__bf16)f1.w;                       \
        *(bf16x8*)(lds + (b) * 16384 + d0) = p;                     \
        p[0]=(__bf16)f2.x; p[1]=(__bf16)f2.y; p[2]=(__bf16)f2.z;    \
        p[3]=(__bf16)f2.w; p[4]=(__bf16)f3.x; p[5]=(__bf16)f3.y;    \
        p[6]=(__bf16)f3.z; p[7]=(__bf16)f3.w;                       \
        *(bf16x8*)(lds + (b) * 16384 + d1) = p;                     \
    }

    // B fragment base pointers (per wave, per nt): contiguous 1KB per fragment
    const __bf16* pV0 = Wfrag + (size_t)(2 * w + 0) * 8192 + l * 8;
    const __bf16* pV1 = Wfrag + (size_t)(2 * w + 1) * 8192 + l * 8;
    const __bf16* pU0 = pV0 + 131072;
    const __bf16* pU1 = pV1 + 131072;

    f32x4 aV[4][2], aU[4][2];
#pragma unroll
    for (int mt = 0; mt < 4; ++mt)
#pragma unroll
        for (int nt = 0; nt < 2; ++nt) {
            aV[mt][nt] = (f32x4){0.f, 0.f, 0.f, 0.f};
            aU[mt][nt] = (f32x4){0.f, 0.f, 0.f, 0.f};
        }

    LOADC(0);
    STOREC(0);
    __syncthreads();

#pragma unroll
    for (int kc = 0; kc < 4; ++kc) {
        if (kc < 3) LOADC(kc + 1);           // issue next-chunk global loads
        const unsigned base = (unsigned)((kc & 1) * 16384);
#pragma unroll
        for (int kk = 0; kk < 4; ++kk) {
            bf16x8 a[4];
#pragma unroll
            for (int mt = 0; mt < 4; ++mt) {
                int r = mt * 16 + lr;
                a[mt] = *(const bf16x8*)(lds + base + r * 256 +
                                         ((((kk << 2) + lg) ^ (r & 15)) << 4));
            }
            const int kb = (kc << 2) + kk;
            bf16x8 bv0 = *(const bf16x8*)(pV0 + kb * 512);
            bf16x8 bv1 = *(const bf16x8*)(pV1 + kb * 512);
            bf16x8 bu0 = *(const bf16x8*)(pU0 + kb * 512);
            bf16x8 bu1 = *(const bf16x8*)(pU1 + kb * 512);
#pragma unroll
            for (int mt = 0; mt < 4; ++mt) {
                aV[mt][0] = __builtin_amdgcn_mfma_f32_16x16x32_bf16(a[mt], bv0, aV[mt][0], 0, 0, 0);
                aV[mt][1] = __builtin_amdgcn_mfma_f32_16x16x32_bf16(a[mt], bv1, aV[mt][1], 0, 0, 0);
                aU[mt][0] = __builtin_amdgcn_mfma_f32_16x16x32_bf16(a[mt], bu0, aU[mt][0], 0, 0, 0);
                aU[mt][1] = __builtin_amdgcn_mfma_f32_16x16x32_bf16(a[mt], bu1, aU[mt][1], 0, 0, 0);
            }
        }
        __syncthreads();                     // all waves done with other buffer
        if (kc < 3) { STOREC((kc + 1) & 1); __syncthreads(); }
    }
#undef LOADC
#undef STOREC

    // ---- epilogue: C(row,col): col = 32w + nt*16 + lr, row = mt*16 + lg*4 + r
    float rowsum[4][4];
#pragma unroll
    for (int mt = 0; mt < 4; ++mt)
#pragma unroll
        for (int r = 0; r < 4; ++r) rowsum[mt][r] = 0.f;

#pragma unroll
    for (int nt = 0; nt < 2; ++nt) {
        int col = w * 32 + nt * 16 + lr;
        float bv = Vb[col];
        float bu = Ub[col];
        float wj = ww[col];
#pragma unroll
        for (int mt = 0; mt < 4; ++mt)
#pragma unroll
            for (int r = 0; r < 4; ++r) {
                float zv = aV[mt][nt][r] + bv;
                float zu = aU[mt][nt][r] + bu;
                float t  = 1.f - 2.f * __builtin_amdgcn_rcpf(__expf(2.f * zv) + 1.f);
                float sg = __builtin_amdgcn_rcpf(1.f + __expf(-zu));
                rowsum[mt][r] += t * sg * wj;
            }
    }

#pragma unroll
    for (int mt = 0; mt < 4; ++mt)
#pragma unroll
        for (int r = 0; r < 4; ++r) {
            float v = rowsum[mt][r];
            v += __shfl_xor(v, 1, 64);
            v += __shfl_xor(v, 2, 64);
            v += __shfl_xor(v, 4, 64);
            v += __shfl_xor(v, 8, 64);
            rowsum[mt][r] = v;
        }

    float* sred = (float*)lds;               // [8 waves][64 rows] (after barrier)
    if (lr == 0) {
#pragma unroll
        for (int mt = 0; mt < 4; ++mt)
#pragma unroll
            for (int r = 0; r < 4; ++r)
                sred[w * 64 + mt * 16 + lg * 4 + r] = rowsum[mt][r];
    }
    __syncthreads();
    if (tid < 64) {
        float s = 0.f;
#pragma unroll
        for (int ww_ = 0; ww_ < 8; ++ww_) s += sred[ww_ * 64 + tid];
        int node = row0 + tid;
        if (node < M) s_out[node] = s;       // w_b omitted: softmax-invariant
    }
}

// ---------------------------------------------------------------------------
// Kernel 2: per-segment softmax (ptr arrives int32). Last block also writes
// att for tail nodes [ptr[nseg], ntot) without including them in reductions.
// ---------------------------------------------------------------------------
__global__ __launch_bounds__(256) void seg_softmax(
    const float* __restrict__ s, const int* __restrict__ ptr,
    float* __restrict__ att, int nseg, int ntot) {
    __shared__ float red[4];
    __shared__ float bmax, bsum;
    int g = blockIdx.x, tid = threadIdx.x;
    int i0 = ptr[g], i1 = ptr[g + 1];
    if (i0 < 0) i0 = 0;  if (i0 > ntot) i0 = ntot;
    if (i1 < i0) i1 = i0; if (i1 > ntot) i1 = ntot;
    int iw1 = (g == nseg - 1) ? ntot : i1;

    float m = -3.4e38f;
    for (int i = i0 + tid; i < i1; i += 256) m = fmaxf(m, s[i]);
    for (int o = 1; o < 64; o <<= 1) m = fmaxf(m, __shfl_xor(m, o, 64));
    if ((tid & 63) == 0) red[tid >> 6] = m;
    __syncthreads();
    if (tid == 0)
        bmax = fmaxf(fmaxf(red[0], red[1]), fmaxf(red[2], red[3]));
    __syncthreads();
    m = bmax;

    float sum = 0.f;
    for (int i = i0 + tid; i < i1; i += 256) sum += __expf(s[i] - m);
    for (int o = 1; o < 64; o <<= 1) sum += __shfl_xor(sum, o, 64);
    if ((tid & 63) == 0) red[tid >> 6] = sum;
    __syncthreads();
    if (tid == 0) bsum = red[0] + red[1] + red[2] + red[3];
    __syncthreads();
    float inv = 1.f / bsum;

    for (int i = i0 + tid; i < iw1; i += 256) att[i] = __expf(s[i] - m) * inv;
}

// ---------------------------------------------------------------------------
// Kernel 3: x_graphs[g] = sum att[i]*x[i].  float4 loads; thread = (c4, ro):
// dims [4*c4,4*c4+4), rows n0+ro step 4, 4-deep unroll (4 loads in flight).
// Block-level LDS reduction, then 512 scalar atomics per block.
// ---------------------------------------------------------------------------
__global__ __launch_bounds__(512) void seg_weighted_sum(
    const float* __restrict__ x, const float* __restrict__ att,
    const int* __restrict__ ptr, float* __restrict__ xg, int chunks) {
    __shared__ float4 sredv[512];
    const float4* x4 = (const float4*)x;
    int g = blockIdx.x / chunks, c = blockIdx.x % chunks;
    int c4 = threadIdx.x & 127, ro = threadIdx.x >> 7;
    int i0 = ptr[g], i1 = ptr[g + 1];
    int len = i1 - i0;
    int n0 = i0 + (int)(((long long)len * c) / chunks);
    int n1 = i0 + (int)(((long long)len * (c + 1)) / chunks);

    float4 a0 = {0,0,0,0}, a1 = {0,0,0,0}, a2 = {0,0,0,0}, a3 = {0,0,0,0};
    int i = n0 + ro;
    for (; i + 12 < n1; i += 16) {
        float t0 = att[i], t1 = att[i + 4], t2 = att[i + 8], t3 = att[i + 12];
        float4 v0 = x4[(size_t)(i     ) * 128 + c4];
        float4 v1 = x4[(size_t)(i +  4) * 128 + c4];
        float4 v2 = x4[(size_t)(i +  8) * 128 + c4];
        float4 v3 = x4[(size_t)(i + 12) * 128 + c4];
        fma4(a0, t0, v0); fma4(a1, t1, v1); fma4(a2, t2, v2); fma4(a3, t3, v3);
    }
    for (; i < n1; i += 4) fma4(a0, att[i], x4[(size_t)i * 128 + c4]);
    fma4(a0, 1.f, a1); fma4(a2, 1.f, a3); fma4(a0, 1.f, a2);
    sredv[threadIdx.x] = a0;
    __syncthreads();
    if (threadIdx.x < 128) {
        float4 r = sredv[threadIdx.x];
        float4 rb = sredv[threadIdx.x + 128];
        float4 rc = sredv[threadIdx.x + 256];
        float4 rd = sredv[threadIdx.x + 384];
        fma4(r, 1.f, rb); fma4(rc, 1.f, rd); fma4(r, 1.f, rc);
        float* dst = &xg[(size_t)g * 512 + c4 * 4];
        atomicAdd(dst + 0, r.x);
        atomicAdd(dst + 1, r.y);
        atomicAdd(dst + 2, r.z);
        atomicAdd(dst + 3, r.w);
    }
}

extern "C" void kernel_launch(void* const* d_in, const int* in_sizes, int n_in,
                              void* d_out, int out_size, void* d_ws, size_t ws_size,
                              hipStream_t stream) {
    const float* x   = (const float*)d_in[0];
    const int*   ptr = (const int*)d_in[1];   // harness: integer -> int32
    const float* Vw  = (const float*)d_in[2];
    const float* Vb  = (const float*)d_in[3];
    const float* Uw  = (const float*)d_in[4];
    const float* Ub  = (const float*)d_in[5];
    const float* ww  = (const float*)d_in[6];
    // d_in[7] = w_b: adds a constant to every score -> cancels in softmax.

    const int M    = in_sizes[0] / 512;   // 100000 nodes
    const int nseg = in_sizes[1] - 1;     // 64 graphs

    float* att = (float*)d_out;           // output 0: M floats
    float* xg  = (float*)d_out + M;       // output 1: nseg*512 floats

    __bf16* Wfrag = (__bf16*)d_ws;                         // 256K bf16 = 512KB
    float*  s_all = (float*)(Wfrag + 262144);              // M f32

    prep_weights<<<128, 256, 0, stream>>>(Vw, Uw, Wfrag);
    gemm_score<<<(M + 63) / 64, 512, 0, stream>>>(x, Wfrag, Vb, Ub, ww, s_all, M);
    seg_softmax<<<nseg, 256, 0, stream>>>(s_all, ptr, att, nseg, M);
    hipMemsetAsync(xg, 0, (size_t)nseg * 512 * sizeof(float), stream);
    const int CH = 16;
    seg_weighted_sum<<<nseg * CH, 512, 0, stream>>>(x, att, ptr, xg, CH);
}

// Round 7
// 375.335 us; speedup vs baseline: 1.2672x; 1.0162x over previous
//
#include <hip/hip_runtime.h>

typedef __attribute__((ext_vector_type(8))) __bf16 bf16x8;
typedef __attribute__((ext_vector_type(4))) float f32x4;

__device__ __forceinline__ void fma4(float4& a, float t, const float4 v) {
    a.x += t * v.x; a.y += t * v.y; a.z += t * v.z; a.w += t * v.w;
}

// ---------------------------------------------------------------------------
// Kernel 0: weight prep -> MFMA-fragment-order bf16 layout.
// Fragment f = ((m*16+cb)*16+kb): 64 lanes x 16B, lane l holds
// col = cb*16 + (l&15), k = kb*32 + (l>>4)*8 + j  (j=0..7).
// A wave's B-load is then a contiguous 1KB global read.
// ---------------------------------------------------------------------------
__global__ __launch_bounds__(256) void prep_weights(
    const float* __restrict__ Vw, const float* __restrict__ Uw,
    __bf16* __restrict__ Wfrag) {
    int id = blockIdx.x * 256 + threadIdx.x;     // 32768 threads
    int m  = id >> 14;
    int cb = (id >> 10) & 15;
    int kb = (id >> 6) & 15;
    int l  = id & 63;
    int col = cb * 16 + (l & 15);
    int k0  = kb * 32 + (l >> 4) * 8;
    const float* src = (m ? Uw : Vw) + (size_t)k0 * 256 + col;
    bf16x8 p;
#pragma unroll
    for (int j = 0; j < 8; ++j) p[j] = (__bf16)src[j * 256];
    *(bf16x8*)(Wfrag + (size_t)id * 8) = p;
}

// ---------------------------------------------------------------------------
// Kernel 1: fused GEMM + gated score. BM=64, full K=512 staged up front into
// 4 x 16KB LDS sub-buffers (2-deep load/store pipeline; staging regs dead at
// the single barrier -> no spill at 128-VGPR cap). 8 waves; wave w owns V and
// U cols [32w, 32w+32). B from fragment-order global (1KB/wave, L2-resident).
// Epilogue: s_row = sum_j tanh(zV_j)*sigmoid(zU_j)*w_j, branch-free exp/rcp.
// ---------------------------------------------------------------------------
__global__ __launch_bounds__(512, 4) void gemm_score(
    const float* __restrict__ x, const __bf16* __restrict__ Wfrag,
    const float* __restrict__ Vb, const float* __restrict__ Ub,
    const float* __restrict__ ww, float* __restrict__ s_out, int M) {
    __shared__ unsigned char lds[4 * 16384];     // 4 x (64 rows x 128 k x bf16)
    const int tid  = threadIdx.x;
    const int row0 = blockIdx.x * 64;
    const int l  = tid & 63;
    const int w  = tid >> 6;
    const int lr = l & 15;
    const int lg = l >> 4;

    // staging geometry: per sub-buffer 1024 16B-chunks; thread -> rows {r0, r1}
    const int r0 = tid >> 4;                 // 0..31
    const int r1 = r0 + 32;                  // 32..63
    const int c16 = tid & 15;
    int g0 = row0 + r0; if (g0 >= M) g0 = M - 1;
    int g1 = row0 + r1; if (g1 >= M) g1 = M - 1;
    const float* src0 = x + (size_t)g0 * 512 + c16 * 8;
    const float* src1 = x + (size_t)g1 * 512 + c16 * 8;
    const unsigned d0 = (unsigned)(r0 * 256 + ((c16 ^ (r0 & 15)) << 4));
    const unsigned d1 = (unsigned)(r1 * 256 + ((c16 ^ (r1 & 15)) << 4));

#define LOADC(S, kc)                                                \
    float4 fa##S = *(const float4*)(src0 + (kc) * 128);             \
    float4 fb##S = *(const float4*)(src0 + (kc) * 128 + 4);         \
    float4 fc##S = *(const float4*)(src1 + (kc) * 128);             \
    float4 fd##S = *(const float4*)(src1 + (kc) * 128 + 4);
#define STOREC(S, kc)                                               \
    {                                                               \
        bf16x8 p;                                                   \
        p[0]=(__bf16)fa##S.x; p[1]=(__bf16)fa##S.y;                 \
        p[2]=(__bf16)fa##S.z; p[3]=(__bf16)fa##S.w;                 \
        p[4]=(__bf16)fb##S.x; p[5]=(__bf16)fb##S.y;                 \
        p[6]=(__bf16)fb##S.z; p[7]=(__bf16)fb##S.w;                 \
        *(bf16x8*)(lds + (kc) * 16384 + d0) = p;                    \
        p[0]=(__bf16)fc##S.x; p[1]=(__bf16)fc##S.y;                 \
        p[2]=(__bf16)fc##S.z; p[3]=(__bf16)fc##S.w;                 \
        p[4]=(__bf16)fd##S.x; p[5]=(__bf16)fd##S.y;                 \
        p[6]=(__bf16)fd##S.z; p[7]=(__bf16)fd##S.w;                 \
        *(bf16x8*)(lds + (kc) * 16384 + d1) = p;                    \
    }

    // 2-deep staging pipeline: <=2 kc-chunks (32 f32 regs) in flight.
    LOADC(0, 0); LOADC(1, 1);
    STOREC(0, 0);
    LOADC(2, 2);
    STOREC(1, 1);
    LOADC(3, 3);
    STOREC(2, 2);
    STOREC(3, 3);
#undef LOADC
#undef STOREC

    // B fragment base pointers (per wave, per nt): contiguous 1KB per fragment
    const __bf16* pV0 = Wfrag + (size_t)(2 * w + 0) * 8192 + l * 8;
    const __bf16* pV1 = Wfrag + (size_t)(2 * w + 1) * 8192 + l * 8;
    const __bf16* pU0 = pV0 + 131072;
    const __bf16* pU1 = pV1 + 131072;

    f32x4 aV[4][2], aU[4][2];
#pragma unroll
    for (int mt = 0; mt < 4; ++mt)
#pragma unroll
        for (int nt = 0; nt < 2; ++nt) {
            aV[mt][nt] = (f32x4){0.f, 0.f, 0.f, 0.f};
            aU[mt][nt] = (f32x4){0.f, 0.f, 0.f, 0.f};
        }

    __syncthreads();                          // staging complete

#pragma unroll
    for (int kc = 0; kc < 4; ++kc) {
        const unsigned base = (unsigned)(kc * 16384);
#pragma unroll
        for (int kk = 0; kk < 4; ++kk) {
            bf16x8 a[4];
#pragma unroll
            for (int mt = 0; mt < 4; ++mt) {
                int r = mt * 16 + lr;
                a[mt] = *(const bf16x8*)(lds + base + r * 256 +
                                         ((((kk << 2) + lg) ^ (r & 15)) << 4));
            }
            const int kb = (kc << 2) + kk;
            bf16x8 bv0 = *(const bf16x8*)(pV0 + kb * 512);
            bf16x8 bv1 = *(const bf16x8*)(pV1 + kb * 512);
            bf16x8 bu0 = *(const bf16x8*)(pU0 + kb * 512);
            bf16x8 bu1 = *(const bf16x8*)(pU1 + kb * 512);
#pragma unroll
            for (int mt = 0; mt < 4; ++mt) {
                aV[mt][0] = __builtin_amdgcn_mfma_f32_16x16x32_bf16(a[mt], bv0, aV[mt][0], 0, 0, 0);
                aV[mt][1] = __builtin_amdgcn_mfma_f32_16x16x32_bf16(a[mt], bv1, aV[mt][1], 0, 0, 0);
                aU[mt][0] = __builtin_amdgcn_mfma_f32_16x16x32_bf16(a[mt], bu0, aU[mt][0], 0, 0, 0);
                aU[mt][1] = __builtin_amdgcn_mfma_f32_16x16x32_bf16(a[mt], bu1, aU[mt][1], 0, 0, 0);
            }
        }
    }

    // ---- epilogue: C(row,col): col = 32w + nt*16 + lr, row = mt*16 + lg*4 + r
    float rowsum[4][4];
#pragma unroll
    for (int mt = 0; mt < 4; ++mt)
#pragma unroll
        for (int r = 0; r < 4; ++r) rowsum[mt][r] = 0.f;

#pragma unroll
    for (int nt = 0; nt < 2; ++nt) {
        int col = w * 32 + nt * 16 + lr;
        float bv = Vb[col];
        float bu = Ub[col];
        float wj = ww[col];
#pragma unroll
        for (int mt = 0; mt < 4; ++mt)
#pragma unroll
            for (int r = 0; r < 4; ++r) {
                float zv = aV[mt][nt][r] + bv;
                float zu = aU[mt][nt][r] + bu;
                float t  = 1.f - 2.f * __builtin_amdgcn_rcpf(__expf(2.f * zv) + 1.f);
                float sg = __builtin_amdgcn_rcpf(1.f + __expf(-zu));
                rowsum[mt][r] += t * sg * wj;
            }
    }

#pragma unroll
    for (int mt = 0; mt < 4; ++mt)
#pragma unroll
        for (int r = 0; r < 4; ++r) {
            float v = rowsum[mt][r];
            v += __shfl_xor(v, 1, 64);
            v += __shfl_xor(v, 2, 64);
            v += __shfl_xor(v, 4, 64);
            v += __shfl_xor(v, 8, 64);
            rowsum[mt][r] = v;
        }

    __syncthreads();                          // all waves done reading A tile
    float* sred = (float*)lds;                // [8 waves][64 rows]
    if (lr == 0) {
#pragma unroll
        for (int mt = 0; mt < 4; ++mt)
#pragma unroll
            for (int r = 0; r < 4; ++r)
                sred[w * 64 + mt * 16 + lg * 4 + r] = rowsum[mt][r];
    }
    __syncthreads();
    if (tid < 64) {
        float s = 0.f;
#pragma unroll
        for (int ww_ = 0; ww_ < 8; ++ww_) s += sred[ww_ * 64 + tid];
        int node = row0 + tid;
        if (node < M) s_out[node] = s;        // w_b omitted: softmax-invariant
    }
}

// ---------------------------------------------------------------------------
// Kernel 2: per-segment softmax (ptr arrives int32). Last block also writes
// att for tail nodes [ptr[nseg], ntot) without including them in reductions.
// ---------------------------------------------------------------------------
__global__ __launch_bounds__(256) void seg_softmax(
    const float* __restrict__ s, const int* __restrict__ ptr,
    float* __restrict__ att, int nseg, int ntot) {
    __shared__ float red[4];
    __shared__ float bmax, bsum;
    int g = blockIdx.x, tid = threadIdx.x;
    int i0 = ptr[g], i1 = ptr[g + 1];
    if (i0 < 0) i0 = 0;  if (i0 > ntot) i0 = ntot;
    if (i1 < i0) i1 = i0; if (i1 > ntot) i1 = ntot;
    int iw1 = (g == nseg - 1) ? ntot : i1;

    float m = -3.4e38f;
    for (int i = i0 + tid; i < i1; i += 256) m = fmaxf(m, s[i]);
    for (int o = 1; o < 64; o <<= 1) m = fmaxf(m, __shfl_xor(m, o, 64));
    if ((tid & 63) == 0) red[tid >> 6] = m;
    __syncthreads();
    if (tid == 0)
        bmax = fmaxf(fmaxf(red[0], red[1]), fmaxf(red[2], red[3]));
    __syncthreads();
    m = bmax;

    float sum = 0.f;
    for (int i = i0 + tid; i < i1; i += 256) sum += __expf(s[i] - m);
    for (int o = 1; o < 64; o <<= 1) sum += __shfl_xor(sum, o, 64);
    if ((tid & 63) == 0) red[tid >> 6] = sum;
    __syncthreads();
    if (tid == 0) bsum = red[0] + red[1] + red[2] + red[3];
    __syncthreads();
    float inv = 1.f / bsum;

    for (int i = i0 + tid; i < iw1; i += 256) att[i] = __expf(s[i] - m) * inv;
}

// ---------------------------------------------------------------------------
// Kernel 3: x_graphs[g] = sum att[i]*x[i].  float4 loads; thread = (c4, ro):
// dims [4*c4,4*c4+4), rows n0+ro step 4, 4-deep unroll (4 loads in flight).
// Block-level LDS reduction, then 512 scalar atomics per block.
// ---------------------------------------------------------------------------
__global__ __launch_bounds__(512) void seg_weighted_sum(
    const float* __restrict__ x, const float* __restrict__ att,
    const int* __restrict__ ptr, float* __restrict__ xg, int chunks) {
    __shared__ float4 sredv[512];
    const float4* x4 = (const float4*)x;
    int g = blockIdx.x / chunks, c = blockIdx.x % chunks;
    int c4 = threadIdx.x & 127, ro = threadIdx.x >> 7;
    int i0 = ptr[g], i1 = ptr[g + 1];
    int len = i1 - i0;
    int n0 = i0 + (int)(((long long)len * c) / chunks);
    int n1 = i0 + (int)(((long long)len * (c + 1)) / chunks);

    float4 a0 = {0,0,0,0}, a1 = {0,0,0,0}, a2 = {0,0,0,0}, a3 = {0,0,0,0};
    int i = n0 + ro;
    for (; i + 12 < n1; i += 16) {
        float t0 = att[i], t1 = att[i + 4], t2 = att[i + 8], t3 = att[i + 12];
        float4 v0 = x4[(size_t)(i     ) * 128 + c4];
        float4 v1 = x4[(size_t)(i +  4) * 128 + c4];
        float4 v2 = x4[(size_t)(i +  8) * 128 + c4];
        float4 v3 = x4[(size_t)(i + 12) * 128 + c4];
        fma4(a0, t0, v0); fma4(a1, t1, v1); fma4(a2, t2, v2); fma4(a3, t3, v3);
    }
    for (; i < n1; i += 4) fma4(a0, att[i], x4[(size_t)i * 128 + c4]);
    fma4(a0, 1.f, a1); fma4(a2, 1.f, a3); fma4(a0, 1.f, a2);
    sredv[threadIdx.x] = a0;
    __syncthreads();
    if (threadIdx.x < 128) {
        float4 r = sredv[threadIdx.x];
        float4 rb = sredv[threadIdx.x + 128];
        float4 rc = sredv[threadIdx.x + 256];
        float4 rd = sredv[threadIdx.x + 384];
        fma4(r, 1.f, rb); fma4(rc, 1.f, rd); fma4(r, 1.f, rc);
        float* dst = &xg[(size_t)g * 512 + c4 * 4];
        atomicAdd(dst + 0, r.x);
        atomicAdd(dst + 1, r.y);
        atomicAdd(dst + 2, r.z);
        atomicAdd(dst + 3, r.w);
    }
}

extern "C" void kernel_launch(void* const* d_in, const int* in_sizes, int n_in,
                              void* d_out, int out_size, void* d_ws, size_t ws_size,
                              hipStream_t stream) {
    const float* x   = (const float*)d_in[0];
    const int*   ptr = (const int*)d_in[1];   // harness: integer -> int32
    const float* Vw  = (const float*)d_in[2];
    const float* Vb  = (const float*)d_in[3];
    const float* Uw  = (const float*)d_in[4];
    const float* Ub  = (const float*)d_in[5];
    const float* ww  = (const float*)d_in[6];
    // d_in[7] = w_b: adds a constant to every score -> cancels in softmax.

    const int M    = in_sizes[0] / 512;   // 100000 nodes
    const int nseg = in_sizes[1] - 1;     // 64 graphs

    float* att = (float*)d_out;           // output 0: M floats
    float* xg  = (float*)d_out + M;       // output 1: nseg*512 floats

    __bf16* Wfrag = (__bf16*)d_ws;                         // 256K bf16 = 512KB
    float*  s_all = (float*)(Wfrag + 262144);              // M f32

    prep_weights<<<128, 256, 0, stream>>>(Vw, Uw, Wfrag);
    gemm_score<<<(M + 63) / 64, 512, 0, stream>>>(x, Wfrag, Vb, Ub, ww, s_all, M);
    seg_softmax<<<nseg, 256, 0, stream>>>(s_all, ptr, att, nseg, M);
    hipMemsetAsync(xg, 0, (size_t)nseg * 512 * sizeof(float), stream);
    const int CH = 16;
    seg_weighted_sum<<<nseg * CH, 512, 0, stream>>>(x, att, ptr, xg, CH);
}